// Round 8
// baseline (378.492 us; speedup 1.0000x reference)
//
#include <hip/hip_runtime.h>

// Problem constants
#define B_N 4096
#define T_N 512
// Output layout (floats): final (B,T,2) | fwd_out (B,2) | noise (B,T,1)
#define FWD_OFF   (B_N * T_N * 2)        // 4194304
#define NOISE_OFF (FWD_OFF + B_N * 2)    // 4202496

#define S_SIG  (-1.4426950408889634f)   // -log2(e)
#define S_TANH (-2.8853900817779268f)   // -2*log2(e)

typedef float v2f __attribute__((ext_vector_type(2)));
__device__ __forceinline__ v2f mkv2(float a, float b) { v2f r; r.x = a; r.y = b; return r; }

// packed fp32 ops (v_pk_fma_f32 / v_pk_mul_f32) — halve dot-product issue count.
// pk_mul as the first dot term kills the mkv2(bias,0) accumulator-init movs;
// the bias is folded into the horizontal sum (x+y+b -> v_add3).
__device__ __forceinline__ v2f pk_fma(v2f a, v2f b, v2f c) {
    v2f d;
    asm("v_pk_fma_f32 %0, %1, %2, %3" : "=v"(d) : "v"(a), "v"(b), "v"(c));
    return d;
}
__device__ __forceinline__ v2f pk_mul(v2f a, v2f b) {
    v2f d;
    asm("v_pk_mul_f32 %0, %1, %2" : "=v"(d) : "v"(a), "v"(b));
    return d;
}

// act on pre-scaled accumulator: returns fma(A, rcp(1+exp2(a)), B)
// A=1,B=0  -> sigmoid(v) where a = -log2e*v
// A=2,B=-1 -> tanh(v)    where a = -2log2e*v
__device__ __forceinline__ float act_ab(float a, float A, float Bc) {
    float r = __builtin_amdgcn_rcpf(1.0f + __builtin_amdgcn_exp2f(a));
    return fmaf(A, r, Bc);
}
__device__ __forceinline__ float sig_acc(float a) {
    return __builtin_amdgcn_rcpf(1.0f + __builtin_amdgcn_exp2f(a));
}
__device__ __forceinline__ float tanh_acc(float a) {
    return fmaf(2.0f, __builtin_amdgcn_rcpf(1.0f + __builtin_amdgcn_exp2f(a)), -1.0f);
}
__device__ __forceinline__ float tanh_nat(float v) {
    return tanh_acc(v * S_TANH);
}

// ---- DPP cross-lane (all-VALU, zero DS in the kernel) ----
// ROW_ROR:N (0x120+N): dst lane i <- src lane (i-N)&15 within each 16-lane row
// ROW_NEWBCAST:J (0x150+J, gfx90a+): dst lane i <- src lane J of its 16-lane row
template<int CTRL>
__device__ __forceinline__ float dppf(float v) {
    return __int_as_float(__builtin_amdgcn_update_dpp(
        __float_as_int(v), __float_as_int(v), CTRL, 0xF, 0xF, false));
}

// Round-7 structure (299.9 us steady, VALUBusy 77%) plus:
//  - encoder layer-pipelining: body(t) = { L1 for step t-1 || L0 for step t },
//    both chains independent (encoder has no h1->L0 feedback) -> chain ~halved
//  - pk_mul accumulator starts (no mkv2(bias,0) movs; bias folded via add3)
//  - decoder noise dot hoisted into the NEXT iteration's L0-latency window
//    (it previously sat on the serial tail before the flush-branch boundary)
// 16 lanes/elem, 4 elems/wave, 1 wave/SIMD, all cross-lane via DPP.
__global__ __attribute__((amdgpu_waves_per_eu(1, 1))) __launch_bounds__(256)
void fused_kernel(
    const float* __restrict__ x,
    const float* __restrict__ eWih0, const float* __restrict__ eWhh0,
    const float* __restrict__ ebih0, const float* __restrict__ ebhh0,
    const float* __restrict__ eWih1, const float* __restrict__ eWhh1,
    const float* __restrict__ ebih1, const float* __restrict__ ebhh1,
    const float* __restrict__ dWih0, const float* __restrict__ dWhh0,
    const float* __restrict__ dbih0, const float* __restrict__ dbhh0,
    const float* __restrict__ dWih1, const float* __restrict__ dWhh1,
    const float* __restrict__ dbih1, const float* __restrict__ dbhh1,
    const float* __restrict__ fcW, const float* __restrict__ fcb,
    const float* __restrict__ outW, const float* __restrict__ outb,
    float* __restrict__ out)
{
    const int tid  = blockIdx.x * 256 + threadIdx.x;
    const int b    = tid >> 4;     // batch element
    const int lane = tid & 15;     // 16 lanes per element (= one DPP row)

    // =================== ENCODER: gate-row-parallel (H=4) ===================
    const int kk = lane >> 2;
    const float sc = (kk == 2) ? S_TANH : S_SIG;
    const float Ak = (kk == 2) ? 2.0f : 1.0f;
    const float Bk = (kk == 2) ? -1.0f : 0.0f;

    v2f h0p[2] = {mkv2(0.f, 0.f), mkv2(0.f, 0.f)};
    v2f h1p[2] = {mkv2(0.f, 0.f), mkv2(0.f, 0.f)};
    float c0 = 0.f, c1 = 0.f;
    float fw0, fw1;

    {
        const int r = lane;
        float ew0 = eWih0[r] * sc;
        float eb0 = (ebih0[r] + ebhh0[r]) * sc;
        float eb1 = (ebih1[r] + ebhh1[r]) * sc;
        v2f ewh0p[2], ewi1p[2], ewh1p[2];
#pragma unroll
        for (int j = 0; j < 2; ++j) {
            ewh0p[j] = mkv2(eWhh0[r * 4 + 2 * j], eWhh0[r * 4 + 2 * j + 1]) * sc;
            ewi1p[j] = mkv2(eWih1[r * 4 + 2 * j], eWih1[r * 4 + 2 * j + 1]) * sc;
            ewh1p[j] = mkv2(eWhh1[r * 4 + 2 * j], eWhh1[r * 4 + 2 * j + 1]) * sc;
        }

        // L0 gate pre-activation for step t (reads current h0p = h0(t-1))
        auto l0_dots = [&](float xc) -> float {
            v2f gg = pk_mul(ewh0p[0], h0p[0]);
            gg = pk_fma(ewh0p[1], h0p[1], gg);
            return gg.x + gg.y + fmaf(ew0, xc, eb0);
        };
        // L1 gate pre-activation for step t-1 (reads h0p = h0(t-1), h1p = h1(t-2))
        auto l1_dots = [&]() -> float {
            v2f qq = pk_mul(ewi1p[0], h0p[0]);
            qq = pk_fma(ewi1p[1], h0p[1], qq);
            qq = pk_fma(ewh1p[0], h1p[0], qq);
            qq = pk_fma(ewh1p[1], h1p[1], qq);
            return qq.x + qq.y + eb1;
        };
        // act + cell update + h broadcast for one layer
        auto finish = [&](float g, float& c, v2f* hp) {
            float gate = act_ab(g, Ak, Bk);
            // DPP row rotate (src lane = (i-N)&15): on lanes 0..3:
            // ror:12 -> i+4 (f), ror:8 -> i+8 (g), ror:4 -> i+12 (o)
            float fv = dppf<0x12C>(gate);
            float gv = dppf<0x128>(gate);
            float ov = dppf<0x124>(gate);
            c = fmaf(fv, c, gate * gv);       // valid on lanes 0..3 (gate = i there)
            float hu = ov * tanh_nat(c);
            hp[0].x = dppf<0x150>(hu); hp[0].y = dppf<0x151>(hu);
            hp[1].x = dppf<0x152>(hu); hp[1].y = dppf<0x153>(hu);
        };
        // pipelined body: issue BOTH dot blocks (independent), then both chains
        auto ebody = [&](float xc) {
            float g1 = l1_dots();             // L1, step t-1
            float g0 = l0_dots(xc);           // L0, step t
            finish(g0, c0, h0p);              // -> h0(t)
            finish(g1, c1, h1p);              // -> h1(t-1)
        };

        const float4* __restrict__ xq4 = (const float4*)(x + (long)b * T_N);
        float4 xq = xq4[0];
        float4 xn = xq4[1];

        // t=0 peel: L0 only (h1(-1)=0 state preserved)
        { float g0 = l0_dots(xq.x); finish(g0, c0, h0p); }
        ebody(xq.y); ebody(xq.z); ebody(xq.w);           // t=1..3
        xq = xn;
#pragma unroll 1
        for (int tb = 1; tb < T_N / 4; ++tb) {           // t=4..511
            xn = (tb + 1 < T_N / 4) ? xq4[tb + 1] : xq;  // prefetch
            ebody(xq.x); ebody(xq.y); ebody(xq.z); ebody(xq.w);
            xq = xn;
        }
        // epilogue: L1 for step 511
        { float g1 = l1_dots(); finish(g1, c1, h1p); }

        // fwd_out = h1 @ fc_W.T + fc_b   (computed uniformly on all lanes)
        fw0 = fcb[0];
        fw1 = fcb[1];
        fw0 = fmaf(fcW[0], h1p[0].x, fw0); fw0 = fmaf(fcW[1], h1p[0].y, fw0);
        fw0 = fmaf(fcW[2], h1p[1].x, fw0); fw0 = fmaf(fcW[3], h1p[1].y, fw0);
        fw1 = fmaf(fcW[4], h1p[0].x, fw1); fw1 = fmaf(fcW[5], h1p[0].y, fw1);
        fw1 = fmaf(fcW[6], h1p[1].x, fw1); fw1 = fmaf(fcW[7], h1p[1].y, fw1);
        if (lane == 0) {
            out[FWD_OFF + b * 2 + 0] = fw0;
            out[FWD_OFF + b * 2 + 1] = fw1;
        }
    }

    // =================== DECODER: unit-parallel (H=10) ===================
    // lane = unit (0..9 active; 10..15 shadow 9). All dots packed as v2f.
    const int uc = (lane < 10) ? lane : 9;

    float wih0r[4], b0r[4], b1r[4];
    v2f whh0p[4][5], wih1p[4][5], whh1p[4][5];
#pragma unroll
    for (int k = 0; k < 4; ++k) {
        const int r = k * 10 + uc;
        const float sck = (k == 2) ? S_TANH : S_SIG;
        wih0r[k] = dWih0[r] * sck;
        b0r[k] = (dbih0[r] + dbhh0[r]) * sck;
        b1r[k] = (dbih1[r] + dbhh1[r]) * sck;
#pragma unroll
        for (int j = 0; j < 5; ++j) {
            whh0p[k][j] = mkv2(dWhh0[r * 10 + 2 * j], dWhh0[r * 10 + 2 * j + 1]) * sck;
            wih1p[k][j] = mkv2(dWih1[r * 10 + 2 * j], dWih1[r * 10 + 2 * j + 1]) * sck;
            whh1p[k][j] = mkv2(dWhh1[r * 10 + 2 * j], dWhh1[r * 10 + 2 * j + 1]) * sck;
        }
    }
    v2f outwp[5];
#pragma unroll
    for (int j = 0; j < 5; ++j) outwp[j] = mkv2(outW[2 * j], outW[2 * j + 1]);
    const float outb0 = outb[0];

    // Initial decoder state: encoder finals padded 4 -> 10 with zeros
    v2f dh0p[5], dh1p[5];
    dh0p[0] = h0p[0]; dh0p[1] = h0p[1];
    dh1p[0] = h1p[0]; dh1p[1] = h1p[1];
#pragma unroll
    for (int j = 2; j < 5; ++j) { dh0p[j] = mkv2(0.f, 0.f); dh1p[j] = mkv2(0.f, 0.f); }
    float dc0 = (lane < 4) ? c0 : 0.f;
    float dc1 = (lane < 4) ? c1 : 0.f;

    float my_noise = 0.f;

    for (int t = 0; t < T_N; ++t) {
        const float inp = dh1p[0].x;

        // L1 partial from previous h1 (independent of L0 chain)
        v2f p1[4];
#pragma unroll
        for (int k = 0; k < 4; ++k) {
            p1[k] = pk_mul(whh1p[k][0], dh1p[0]);
#pragma unroll
            for (int j = 1; j < 5; ++j) p1[k] = pk_fma(whh1p[k][j], dh1p[j], p1[k]);
        }

        // L0 gates
        v2f g2[4];
#pragma unroll
        for (int k = 0; k < 4; ++k) {
            g2[k] = pk_mul(whh0p[k][0], dh0p[0]);
#pragma unroll
            for (int j = 1; j < 5; ++j) g2[k] = pk_fma(whh0p[k][j], dh0p[j], g2[k]);
        }

        // hoisted: noise for step t-1 (fills the L0 act-latency window).
        // At t=0 this computes garbage into lane 15's my_noise, but lane 15 is
        // re-selected at t=16 (s=15) BEFORE the first flush -> never stored.
        {
            v2f na = pk_mul(outwp[0], dh1p[0]);
#pragma unroll
            for (int j = 1; j < 5; ++j) na = pk_fma(outwp[j], dh1p[j], na);
            const float nzp = na.x + na.y + outb0;
            my_noise = (((t - 1) & 15) == lane) ? nzp : my_noise;
        }
        if ((t & 15) == 0 && t) {           // flush steps t-16..t-1
            const int idx = b * T_N + (t - 16) + lane;
            out[NOISE_OFF + idx] = my_noise;
            float2 fin;
            fin.x = my_noise + fw0;
            fin.y = my_noise + fw1;
            ((float2*)out)[idx] = fin;
        }

        float iv = sig_acc(g2[0].x + g2[0].y + fmaf(wih0r[0], inp, b0r[0]));
        float fv = sig_acc(g2[1].x + g2[1].y + fmaf(wih0r[1], inp, b0r[1]));
        float gv = tanh_acc(g2[2].x + g2[2].y + fmaf(wih0r[2], inp, b0r[2]));
        float ov = sig_acc(g2[3].x + g2[3].y + fmaf(wih0r[3], inp, b0r[3]));
        dc0 = fmaf(fv, dc0, iv * gv);
        const float h0u = ov * tanh_nat(dc0);
        dh0p[0].x = dppf<0x150>(h0u); dh0p[0].y = dppf<0x151>(h0u);
        dh0p[1].x = dppf<0x152>(h0u); dh0p[1].y = dppf<0x153>(h0u);
        dh0p[2].x = dppf<0x154>(h0u); dh0p[2].y = dppf<0x155>(h0u);
        dh0p[3].x = dppf<0x156>(h0u); dh0p[3].y = dppf<0x157>(h0u);
        dh0p[4].x = dppf<0x158>(h0u); dh0p[4].y = dppf<0x159>(h0u);

        // L1 gates: accumulate the post-broadcast half into p1
#pragma unroll
        for (int k = 0; k < 4; ++k) {
#pragma unroll
            for (int j = 0; j < 5; ++j) p1[k] = pk_fma(wih1p[k][j], dh0p[j], p1[k]);
        }
        iv = sig_acc(p1[0].x + p1[0].y + b1r[0]);
        fv = sig_acc(p1[1].x + p1[1].y + b1r[1]);
        gv = tanh_acc(p1[2].x + p1[2].y + b1r[2]);
        ov = sig_acc(p1[3].x + p1[3].y + b1r[3]);
        dc1 = fmaf(fv, dc1, iv * gv);
        const float h1u = ov * tanh_nat(dc1);
        dh1p[0].x = dppf<0x150>(h1u); dh1p[0].y = dppf<0x151>(h1u);
        dh1p[1].x = dppf<0x152>(h1u); dh1p[1].y = dppf<0x153>(h1u);
        dh1p[2].x = dppf<0x154>(h1u); dh1p[2].y = dppf<0x155>(h1u);
        dh1p[3].x = dppf<0x156>(h1u); dh1p[3].y = dppf<0x157>(h1u);
        dh1p[4].x = dppf<0x158>(h1u); dh1p[4].y = dppf<0x159>(h1u);
    }

    // epilogue: noise for step 511 + final flush (steps 496..511)
    {
        v2f na = pk_mul(outwp[0], dh1p[0]);
#pragma unroll
        for (int j = 1; j < 5; ++j) na = pk_fma(outwp[j], dh1p[j], na);
        const float nz = na.x + na.y + outb0;
        my_noise = (lane == 15) ? nz : my_noise;
        const int idx = b * T_N + (T_N - 16) + lane;
        out[NOISE_OFF + idx] = my_noise;
        float2 fin;
        fin.x = my_noise + fw0;
        fin.y = my_noise + fw1;
        ((float2*)out)[idx] = fin;
    }
}

extern "C" void kernel_launch(void* const* d_in, const int* in_sizes, int n_in,
                              void* d_out, int out_size, void* d_ws, size_t ws_size,
                              hipStream_t stream) {
    const float* x     = (const float*)d_in[0];
    // d_in[1] = context (unused by the reference)
    const float* eWih0 = (const float*)d_in[2];
    const float* eWhh0 = (const float*)d_in[3];
    const float* ebih0 = (const float*)d_in[4];
    const float* ebhh0 = (const float*)d_in[5];
    const float* eWih1 = (const float*)d_in[6];
    const float* eWhh1 = (const float*)d_in[7];
    const float* ebih1 = (const float*)d_in[8];
    const float* ebhh1 = (const float*)d_in[9];
    const float* dWih0 = (const float*)d_in[10];
    const float* dWhh0 = (const float*)d_in[11];
    const float* dbih0 = (const float*)d_in[12];
    const float* dbhh0 = (const float*)d_in[13];
    const float* dWih1 = (const float*)d_in[14];
    const float* dWhh1 = (const float*)d_in[15];
    const float* dbih1 = (const float*)d_in[16];
    const float* dbhh1 = (const float*)d_in[17];
    const float* fcW   = (const float*)d_in[18];
    const float* fcb   = (const float*)d_in[19];
    const float* outW  = (const float*)d_in[20];
    const float* outb  = (const float*)d_in[21];

    float* out = (float*)d_out;

    // 4096 elems x 16 lanes = 65536 threads = 1024 waves = 1 wave/SIMD
    fused_kernel<<<dim3((B_N * 16) / 256), dim3(256), 0, stream>>>(
        x, eWih0, eWhh0, ebih0, ebhh0, eWih1, eWhh1, ebih1, ebhh1,
        dWih0, dWhh0, dbih0, dbhh0, dWih1, dWhh1, dbih1, dbhh1,
        fcW, fcb, outW, outb, out);
}

// Round 9
// 377.609 us; speedup vs baseline: 1.0023x; 1.0023x over previous
//
#include <hip/hip_runtime.h>

// Problem constants
#define B_N 4096
#define T_N 512
// Output layout (floats): final (B,T,2) | fwd_out (B,2) | noise (B,T,1)
#define FWD_OFF   (B_N * T_N * 2)        // 4194304
#define NOISE_OFF (FWD_OFF + B_N * 2)    // 4202496

#define S_SIG  (-1.4426950408889634f)   // -log2(e)
#define S_TANH (-2.8853900817779268f)   // -2*log2(e)

typedef float v2f __attribute__((ext_vector_type(2)));
__device__ __forceinline__ v2f mkv2(float a, float b) { v2f r; r.x = a; r.y = b; return r; }

// packed fp32 ops (v_pk_fma_f32 / v_pk_mul_f32) — halve dot-product issue count.
// pk_mul as the first dot term kills the mkv2(bias,0) accumulator-init movs;
// the bias is folded into the horizontal sum (x+y+b -> v_add3).
__device__ __forceinline__ v2f pk_fma(v2f a, v2f b, v2f c) {
    v2f d;
    asm("v_pk_fma_f32 %0, %1, %2, %3" : "=v"(d) : "v"(a), "v"(b), "v"(c));
    return d;
}
__device__ __forceinline__ v2f pk_mul(v2f a, v2f b) {
    v2f d;
    asm("v_pk_mul_f32 %0, %1, %2" : "=v"(d) : "v"(a), "v"(b));
    return d;
}

// act on pre-scaled accumulator: returns fma(A, rcp(1+exp2(a)), B)
// A=1,B=0  -> sigmoid(v) where a = -log2e*v
// A=2,B=-1 -> tanh(v)    where a = -2log2e*v
__device__ __forceinline__ float act_ab(float a, float A, float Bc) {
    float r = __builtin_amdgcn_rcpf(1.0f + __builtin_amdgcn_exp2f(a));
    return fmaf(A, r, Bc);
}
__device__ __forceinline__ float sig_acc(float a) {
    return __builtin_amdgcn_rcpf(1.0f + __builtin_amdgcn_exp2f(a));
}
__device__ __forceinline__ float tanh_acc(float a) {
    return fmaf(2.0f, __builtin_amdgcn_rcpf(1.0f + __builtin_amdgcn_exp2f(a)), -1.0f);
}
__device__ __forceinline__ float tanh_nat(float v) {
    return tanh_acc(v * S_TANH);
}

// ---- DPP cross-lane (all-VALU, zero DS in the kernel) ----
// ROW_ROR:N (0x120+N): dst lane i <- src lane (i-N)&15 within each 16-lane row
// ROW_NEWBCAST:J (0x150+J, gfx90a+): dst lane i <- src lane J of its 16-lane row
template<int CTRL>
__device__ __forceinline__ float dppf(float v) {
    return __int_as_float(__builtin_amdgcn_update_dpp(
        __float_as_int(v), __float_as_int(v), CTRL, 0xF, 0xF, false));
}

// Round-9 ablation: round-8's pipelined ENCODER (chain ~halved) + round-7's
// DECODER structure (noise dot + flush at the iteration TAIL — round-8's
// mid-loop flush split the loop body and regressed 300->306), keeping the
// pk_mul accumulator starts / bias-fold instruction savings.
// 16 lanes/elem, 4 elems/wave, 1 wave/SIMD, all cross-lane via DPP.
__global__ __attribute__((amdgpu_waves_per_eu(1, 1))) __launch_bounds__(256)
void fused_kernel(
    const float* __restrict__ x,
    const float* __restrict__ eWih0, const float* __restrict__ eWhh0,
    const float* __restrict__ ebih0, const float* __restrict__ ebhh0,
    const float* __restrict__ eWih1, const float* __restrict__ eWhh1,
    const float* __restrict__ ebih1, const float* __restrict__ ebhh1,
    const float* __restrict__ dWih0, const float* __restrict__ dWhh0,
    const float* __restrict__ dbih0, const float* __restrict__ dbhh0,
    const float* __restrict__ dWih1, const float* __restrict__ dWhh1,
    const float* __restrict__ dbih1, const float* __restrict__ dbhh1,
    const float* __restrict__ fcW, const float* __restrict__ fcb,
    const float* __restrict__ outW, const float* __restrict__ outb,
    float* __restrict__ out)
{
    const int tid  = blockIdx.x * 256 + threadIdx.x;
    const int b    = tid >> 4;     // batch element
    const int lane = tid & 15;     // 16 lanes per element (= one DPP row)

    // =================== ENCODER: gate-row-parallel (H=4) ===================
    const int kk = lane >> 2;
    const float sc = (kk == 2) ? S_TANH : S_SIG;
    const float Ak = (kk == 2) ? 2.0f : 1.0f;
    const float Bk = (kk == 2) ? -1.0f : 0.0f;

    v2f h0p[2] = {mkv2(0.f, 0.f), mkv2(0.f, 0.f)};
    v2f h1p[2] = {mkv2(0.f, 0.f), mkv2(0.f, 0.f)};
    float c0 = 0.f, c1 = 0.f;
    float fw0, fw1;

    {
        const int r = lane;
        float ew0 = eWih0[r] * sc;
        float eb0 = (ebih0[r] + ebhh0[r]) * sc;
        float eb1 = (ebih1[r] + ebhh1[r]) * sc;
        v2f ewh0p[2], ewi1p[2], ewh1p[2];
#pragma unroll
        for (int j = 0; j < 2; ++j) {
            ewh0p[j] = mkv2(eWhh0[r * 4 + 2 * j], eWhh0[r * 4 + 2 * j + 1]) * sc;
            ewi1p[j] = mkv2(eWih1[r * 4 + 2 * j], eWih1[r * 4 + 2 * j + 1]) * sc;
            ewh1p[j] = mkv2(eWhh1[r * 4 + 2 * j], eWhh1[r * 4 + 2 * j + 1]) * sc;
        }

        // L0 gate pre-activation for step t (reads current h0p = h0(t-1))
        auto l0_dots = [&](float xc) -> float {
            v2f gg = pk_mul(ewh0p[0], h0p[0]);
            gg = pk_fma(ewh0p[1], h0p[1], gg);
            return gg.x + gg.y + fmaf(ew0, xc, eb0);
        };
        // L1 gate pre-activation for step t-1 (reads h0p = h0(t-1), h1p = h1(t-2))
        auto l1_dots = [&]() -> float {
            v2f qq = pk_mul(ewi1p[0], h0p[0]);
            qq = pk_fma(ewi1p[1], h0p[1], qq);
            qq = pk_fma(ewh1p[0], h1p[0], qq);
            qq = pk_fma(ewh1p[1], h1p[1], qq);
            return qq.x + qq.y + eb1;
        };
        // act + cell update + h broadcast for one layer
        auto finish = [&](float g, float& c, v2f* hp) {
            float gate = act_ab(g, Ak, Bk);
            // DPP row rotate (src lane = (i-N)&15): on lanes 0..3:
            // ror:12 -> i+4 (f), ror:8 -> i+8 (g), ror:4 -> i+12 (o)
            float fv = dppf<0x12C>(gate);
            float gv = dppf<0x128>(gate);
            float ov = dppf<0x124>(gate);
            c = fmaf(fv, c, gate * gv);       // valid on lanes 0..3 (gate = i there)
            float hu = ov * tanh_nat(c);
            hp[0].x = dppf<0x150>(hu); hp[0].y = dppf<0x151>(hu);
            hp[1].x = dppf<0x152>(hu); hp[1].y = dppf<0x153>(hu);
        };
        // pipelined body: issue BOTH dot blocks (independent), then both chains
        auto ebody = [&](float xc) {
            float g1 = l1_dots();             // L1, step t-1
            float g0 = l0_dots(xc);           // L0, step t
            finish(g0, c0, h0p);              // -> h0(t)
            finish(g1, c1, h1p);              // -> h1(t-1)
        };

        const float4* __restrict__ xq4 = (const float4*)(x + (long)b * T_N);
        float4 xq = xq4[0];
        float4 xn = xq4[1];

        // t=0 peel: L0 only (h1(-1)=0 state preserved)
        { float g0 = l0_dots(xq.x); finish(g0, c0, h0p); }
        ebody(xq.y); ebody(xq.z); ebody(xq.w);           // t=1..3
        xq = xn;
#pragma unroll 1
        for (int tb = 1; tb < T_N / 4; ++tb) {           // t=4..511
            xn = (tb + 1 < T_N / 4) ? xq4[tb + 1] : xq;  // prefetch
            ebody(xq.x); ebody(xq.y); ebody(xq.z); ebody(xq.w);
            xq = xn;
        }
        // epilogue: L1 for step 511
        { float g1 = l1_dots(); finish(g1, c1, h1p); }

        // fwd_out = h1 @ fc_W.T + fc_b   (computed uniformly on all lanes)
        fw0 = fcb[0];
        fw1 = fcb[1];
        fw0 = fmaf(fcW[0], h1p[0].x, fw0); fw0 = fmaf(fcW[1], h1p[0].y, fw0);
        fw0 = fmaf(fcW[2], h1p[1].x, fw0); fw0 = fmaf(fcW[3], h1p[1].y, fw0);
        fw1 = fmaf(fcW[4], h1p[0].x, fw1); fw1 = fmaf(fcW[5], h1p[0].y, fw1);
        fw1 = fmaf(fcW[6], h1p[1].x, fw1); fw1 = fmaf(fcW[7], h1p[1].y, fw1);
        if (lane == 0) {
            out[FWD_OFF + b * 2 + 0] = fw0;
            out[FWD_OFF + b * 2 + 1] = fw1;
        }
    }

    // =================== DECODER: unit-parallel (H=10) ===================
    // lane = unit (0..9 active; 10..15 shadow 9). All dots packed as v2f.
    // Round-7 structure: noise dot + flush at the iteration TAIL.
    const int uc = (lane < 10) ? lane : 9;

    float wih0r[4], b0r[4], b1r[4];
    v2f whh0p[4][5], wih1p[4][5], whh1p[4][5];
#pragma unroll
    for (int k = 0; k < 4; ++k) {
        const int r = k * 10 + uc;
        const float sck = (k == 2) ? S_TANH : S_SIG;
        wih0r[k] = dWih0[r] * sck;
        b0r[k] = (dbih0[r] + dbhh0[r]) * sck;
        b1r[k] = (dbih1[r] + dbhh1[r]) * sck;
#pragma unroll
        for (int j = 0; j < 5; ++j) {
            whh0p[k][j] = mkv2(dWhh0[r * 10 + 2 * j], dWhh0[r * 10 + 2 * j + 1]) * sck;
            wih1p[k][j] = mkv2(dWih1[r * 10 + 2 * j], dWih1[r * 10 + 2 * j + 1]) * sck;
            whh1p[k][j] = mkv2(dWhh1[r * 10 + 2 * j], dWhh1[r * 10 + 2 * j + 1]) * sck;
        }
    }
    v2f outwp[5];
#pragma unroll
    for (int j = 0; j < 5; ++j) outwp[j] = mkv2(outW[2 * j], outW[2 * j + 1]);
    const float outb0 = outb[0];

    // Initial decoder state: encoder finals padded 4 -> 10 with zeros
    v2f dh0p[5], dh1p[5];
    dh0p[0] = h0p[0]; dh0p[1] = h0p[1];
    dh1p[0] = h1p[0]; dh1p[1] = h1p[1];
#pragma unroll
    for (int j = 2; j < 5; ++j) { dh0p[j] = mkv2(0.f, 0.f); dh1p[j] = mkv2(0.f, 0.f); }
    float dc0 = (lane < 4) ? c0 : 0.f;
    float dc1 = (lane < 4) ? c1 : 0.f;

    float my_noise = 0.f;

    for (int t = 0; t < T_N; ++t) {
        const float inp = dh1p[0].x;

        // L1 partial from previous h1 (independent of L0 chain)
        v2f p1[4];
#pragma unroll
        for (int k = 0; k < 4; ++k) {
            p1[k] = pk_mul(whh1p[k][0], dh1p[0]);
#pragma unroll
            for (int j = 1; j < 5; ++j) p1[k] = pk_fma(whh1p[k][j], dh1p[j], p1[k]);
        }

        // L0 gates
        v2f g2[4];
#pragma unroll
        for (int k = 0; k < 4; ++k) {
            g2[k] = pk_mul(whh0p[k][0], dh0p[0]);
#pragma unroll
            for (int j = 1; j < 5; ++j) g2[k] = pk_fma(whh0p[k][j], dh0p[j], g2[k]);
        }
        float iv = sig_acc(g2[0].x + g2[0].y + fmaf(wih0r[0], inp, b0r[0]));
        float fv = sig_acc(g2[1].x + g2[1].y + fmaf(wih0r[1], inp, b0r[1]));
        float gv = tanh_acc(g2[2].x + g2[2].y + fmaf(wih0r[2], inp, b0r[2]));
        float ov = sig_acc(g2[3].x + g2[3].y + fmaf(wih0r[3], inp, b0r[3]));
        dc0 = fmaf(fv, dc0, iv * gv);
        const float h0u = ov * tanh_nat(dc0);
        dh0p[0].x = dppf<0x150>(h0u); dh0p[0].y = dppf<0x151>(h0u);
        dh0p[1].x = dppf<0x152>(h0u); dh0p[1].y = dppf<0x153>(h0u);
        dh0p[2].x = dppf<0x154>(h0u); dh0p[2].y = dppf<0x155>(h0u);
        dh0p[3].x = dppf<0x156>(h0u); dh0p[3].y = dppf<0x157>(h0u);
        dh0p[4].x = dppf<0x158>(h0u); dh0p[4].y = dppf<0x159>(h0u);

        // L1 gates: accumulate the post-broadcast half into p1
#pragma unroll
        for (int k = 0; k < 4; ++k) {
#pragma unroll
            for (int j = 0; j < 5; ++j) p1[k] = pk_fma(wih1p[k][j], dh0p[j], p1[k]);
        }
        iv = sig_acc(p1[0].x + p1[0].y + b1r[0]);
        fv = sig_acc(p1[1].x + p1[1].y + b1r[1]);
        gv = tanh_acc(p1[2].x + p1[2].y + b1r[2]);
        ov = sig_acc(p1[3].x + p1[3].y + b1r[3]);
        dc1 = fmaf(fv, dc1, iv * gv);
        const float h1u = ov * tanh_nat(dc1);
        dh1p[0].x = dppf<0x150>(h1u); dh1p[0].y = dppf<0x151>(h1u);
        dh1p[1].x = dppf<0x152>(h1u); dh1p[1].y = dppf<0x153>(h1u);
        dh1p[2].x = dppf<0x154>(h1u); dh1p[2].y = dppf<0x155>(h1u);
        dh1p[3].x = dppf<0x156>(h1u); dh1p[3].y = dppf<0x157>(h1u);
        dh1p[4].x = dppf<0x158>(h1u); dh1p[4].y = dppf<0x159>(h1u);

        // noise_t = dec_out . out_W + out_b (uniform on all 16 lanes)
        v2f na = pk_mul(outwp[0], dh1p[0]);
#pragma unroll
        for (int j = 1; j < 5; ++j) na = pk_fma(outwp[j], dh1p[j], na);
        const float nz = na.x + na.y + outb0;

        // lane u keeps t with t%16==u; flush coalesced every 16 steps
        my_noise = ((t & 15) == lane) ? nz : my_noise;
        if ((t & 15) == 15) {
            const int idx = b * T_N + (t - 15) + lane;
            out[NOISE_OFF + idx] = my_noise;
            float2 fin;
            fin.x = my_noise + fw0;
            fin.y = my_noise + fw1;
            ((float2*)out)[idx] = fin;
        }
    }
}

extern "C" void kernel_launch(void* const* d_in, const int* in_sizes, int n_in,
                              void* d_out, int out_size, void* d_ws, size_t ws_size,
                              hipStream_t stream) {
    const float* x     = (const float*)d_in[0];
    // d_in[1] = context (unused by the reference)
    const float* eWih0 = (const float*)d_in[2];
    const float* eWhh0 = (const float*)d_in[3];
    const float* ebih0 = (const float*)d_in[4];
    const float* ebhh0 = (const float*)d_in[5];
    const float* eWih1 = (const float*)d_in[6];
    const float* eWhh1 = (const float*)d_in[7];
    const float* ebih1 = (const float*)d_in[8];
    const float* ebhh1 = (const float*)d_in[9];
    const float* dWih0 = (const float*)d_in[10];
    const float* dWhh0 = (const float*)d_in[11];
    const float* dbih0 = (const float*)d_in[12];
    const float* dbhh0 = (const float*)d_in[13];
    const float* dWih1 = (const float*)d_in[14];
    const float* dWhh1 = (const float*)d_in[15];
    const float* dbih1 = (const float*)d_in[16];
    const float* dbhh1 = (const float*)d_in[17];
    const float* fcW   = (const float*)d_in[18];
    const float* fcb   = (const float*)d_in[19];
    const float* outW  = (const float*)d_in[20];
    const float* outb  = (const float*)d_in[21];

    float* out = (float*)d_out;

    // 4096 elems x 16 lanes = 65536 threads = 1024 waves = 1 wave/SIMD
    fused_kernel<<<dim3((B_N * 16) / 256), dim3(256), 0, stream>>>(
        x, eWih0, eWhh0, ebih0, ebhh0, eWih1, eWhh1, ebih1, ebhh1,
        dWih0, dWhh0, dbih0, dbhh0, dWih1, dWhh1, dbih1, dbhh1,
        fcW, fcb, outW, outb, out);
}

// Round 10
// 361.169 us; speedup vs baseline: 1.0480x; 1.0455x over previous
//
#include <hip/hip_runtime.h>

// Problem constants
#define B_N 4096
#define T_N 512
// Output layout (floats): final (B,T,2) | fwd_out (B,2) | noise (B,T,1)
#define FWD_OFF   (B_N * T_N * 2)        // 4194304
#define NOISE_OFF (FWD_OFF + B_N * 2)    // 4202496

#define S_SIG  (-1.4426950408889634f)   // -log2(e)
#define S_TANH (-2.8853900817779268f)   // -2*log2(e)

typedef float v2f __attribute__((ext_vector_type(2)));
__device__ __forceinline__ v2f mkv2(float a, float b) { v2f r; r.x = a; r.y = b; return r; }

// NATIVE packed math (round-10 change): plain v2f expressions let clang select
// v_pk_fma_f32 / v_pk_mul_f32 (gfx90a+ ISel, fp-contract on) WITHOUT the
// inline-asm register-allocation constraints that forced v_mov shuffling
// around every dot op (the suspected 3-4x instruction-stream inflation).
__device__ __forceinline__ v2f pk_fma(v2f a, v2f b, v2f c) { return a * b + c; }
__device__ __forceinline__ v2f pk_mul(v2f a, v2f b)        { return a * b; }

// act on pre-scaled accumulator: returns fma(A, rcp(1+exp2(a)), B)
// A=1,B=0  -> sigmoid(v) where a = -log2e*v
// A=2,B=-1 -> tanh(v)    where a = -2log2e*v
__device__ __forceinline__ float act_ab(float a, float A, float Bc) {
    float r = __builtin_amdgcn_rcpf(1.0f + __builtin_amdgcn_exp2f(a));
    return fmaf(A, r, Bc);
}
__device__ __forceinline__ float sig_acc(float a) {
    return __builtin_amdgcn_rcpf(1.0f + __builtin_amdgcn_exp2f(a));
}
__device__ __forceinline__ float tanh_acc(float a) {
    return fmaf(2.0f, __builtin_amdgcn_rcpf(1.0f + __builtin_amdgcn_exp2f(a)), -1.0f);
}
__device__ __forceinline__ float tanh_nat(float v) {
    return tanh_acc(v * S_TANH);
}

// ---- DPP cross-lane (all-VALU, zero DS in the kernel) ----
// ROW_ROR:N (0x120+N): dst lane i <- src lane (i-N)&15 within each 16-lane row
// ROW_NEWBCAST:J (0x150+J, gfx90a+): dst lane i <- src lane J of its 16-lane row
template<int CTRL>
__device__ __forceinline__ float dppf(float v) {
    return __int_as_float(__builtin_amdgcn_update_dpp(
        __float_as_int(v), __float_as_int(v), CTRL, 0xF, 0xF, false));
}

// Round-10 = round-7 structure EXACTLY (best measured: 299.9 us, VALUBusy 77%)
// with asm pk ops -> native v2f arithmetic. Round-8/9 established that both the
// encoder layer-pipelining and the mid-loop flush restructure REGRESS; the
// round-7 serial estep + tail flush is the scheduling optimum for this layout.
// 16 lanes/elem, 4 elems/wave, 1 wave/SIMD, all cross-lane via DPP.
__global__ __attribute__((amdgpu_waves_per_eu(1, 1))) __launch_bounds__(256)
void fused_kernel(
    const float* __restrict__ x,
    const float* __restrict__ eWih0, const float* __restrict__ eWhh0,
    const float* __restrict__ ebih0, const float* __restrict__ ebhh0,
    const float* __restrict__ eWih1, const float* __restrict__ eWhh1,
    const float* __restrict__ ebih1, const float* __restrict__ ebhh1,
    const float* __restrict__ dWih0, const float* __restrict__ dWhh0,
    const float* __restrict__ dbih0, const float* __restrict__ dbhh0,
    const float* __restrict__ dWih1, const float* __restrict__ dWhh1,
    const float* __restrict__ dbih1, const float* __restrict__ dbhh1,
    const float* __restrict__ fcW, const float* __restrict__ fcb,
    const float* __restrict__ outW, const float* __restrict__ outb,
    float* __restrict__ out)
{
    const int tid  = blockIdx.x * 256 + threadIdx.x;
    const int b    = tid >> 4;     // batch element
    const int lane = tid & 15;     // 16 lanes per element (= one DPP row)

    // =================== ENCODER: gate-row-parallel (H=4) ===================
    const int kk = lane >> 2;
    const float sc = (kk == 2) ? S_TANH : S_SIG;
    const float Ak = (kk == 2) ? 2.0f : 1.0f;
    const float Bk = (kk == 2) ? -1.0f : 0.0f;

    v2f h0p[2] = {mkv2(0.f, 0.f), mkv2(0.f, 0.f)};
    v2f h1p[2] = {mkv2(0.f, 0.f), mkv2(0.f, 0.f)};
    float c0 = 0.f, c1 = 0.f;
    float fw0, fw1;

    {
        const int r = lane;
        float ew0 = eWih0[r] * sc;
        float eb0 = (ebih0[r] + ebhh0[r]) * sc;
        float eb1 = (ebih1[r] + ebhh1[r]) * sc;
        v2f ewh0p[2], ewi1p[2], ewh1p[2];
#pragma unroll
        for (int j = 0; j < 2; ++j) {
            ewh0p[j] = mkv2(eWhh0[r * 4 + 2 * j], eWhh0[r * 4 + 2 * j + 1]) * sc;
            ewi1p[j] = mkv2(eWih1[r * 4 + 2 * j], eWih1[r * 4 + 2 * j + 1]) * sc;
            ewh1p[j] = mkv2(eWhh1[r * 4 + 2 * j], eWhh1[r * 4 + 2 * j + 1]) * sc;
        }

        const float4* __restrict__ xq4 = (const float4*)(x + (long)b * T_N);
        float4 xq = xq4[0];

        auto estep = [&](float xc) {
            // L1 partial from previous h1 (independent of L0 chain)
            v2f pp = pk_fma(ewh1p[0], h1p[0], mkv2(eb1, 0.f));
            pp = pk_fma(ewh1p[1], h1p[1], pp);

            // L0 gate-row dot
            v2f gg = pk_fma(ewh0p[0], h0p[0], mkv2(fmaf(ew0, xc, eb0), 0.f));
            gg = pk_fma(ewh0p[1], h0p[1], gg);
            float gate = act_ab(gg.x + gg.y, Ak, Bk);
            // gate combine via DPP row rotate (src lane = (i-N)&15):
            // on lanes 0..3: ror:12 -> i+4 (f), ror:8 -> i+8 (g), ror:4 -> i+12 (o)
            float fv = dppf<0x12C>(gate);
            float gv = dppf<0x128>(gate);
            float ov = dppf<0x124>(gate);
            c0 = fmaf(fv, c0, gate * gv);     // valid on lanes 0..3 (gate = i there)
            float h0u = ov * tanh_nat(c0);
            h0p[0].x = dppf<0x150>(h0u); h0p[0].y = dppf<0x151>(h0u);
            h0p[1].x = dppf<0x152>(h0u); h0p[1].y = dppf<0x153>(h0u);

            // L1 gate-row dot (post-broadcast half)
            v2f qq = pk_fma(ewi1p[0], h0p[0], pp);
            qq = pk_fma(ewi1p[1], h0p[1], qq);
            float gate1 = act_ab(qq.x + qq.y, Ak, Bk);
            fv = dppf<0x12C>(gate1);
            gv = dppf<0x128>(gate1);
            ov = dppf<0x124>(gate1);
            c1 = fmaf(fv, c1, gate1 * gv);
            float h1u = ov * tanh_nat(c1);
            h1p[0].x = dppf<0x150>(h1u); h1p[0].y = dppf<0x151>(h1u);
            h1p[1].x = dppf<0x152>(h1u); h1p[1].y = dppf<0x153>(h1u);
        };

        for (int tb = 0; tb < T_N / 4; ++tb) {
            float4 xn = (tb + 1 < T_N / 4) ? xq4[tb + 1] : xq;  // prefetch
            estep(xq.x); estep(xq.y); estep(xq.z); estep(xq.w);
            xq = xn;
        }

        // fwd_out = h1 @ fc_W.T + fc_b   (computed uniformly on all lanes)
        fw0 = fcb[0];
        fw1 = fcb[1];
        fw0 = fmaf(fcW[0], h1p[0].x, fw0); fw0 = fmaf(fcW[1], h1p[0].y, fw0);
        fw0 = fmaf(fcW[2], h1p[1].x, fw0); fw0 = fmaf(fcW[3], h1p[1].y, fw0);
        fw1 = fmaf(fcW[4], h1p[0].x, fw1); fw1 = fmaf(fcW[5], h1p[0].y, fw1);
        fw1 = fmaf(fcW[6], h1p[1].x, fw1); fw1 = fmaf(fcW[7], h1p[1].y, fw1);
        if (lane == 0) {
            out[FWD_OFF + b * 2 + 0] = fw0;
            out[FWD_OFF + b * 2 + 1] = fw1;
        }
    }

    // =================== DECODER: unit-parallel (H=10) ===================
    // lane = unit (0..9 active; 10..15 shadow 9). All dots packed as v2f.
    const int uc = (lane < 10) ? lane : 9;

    float wih0r[4], b0r[4], b1r[4];
    v2f whh0p[4][5], wih1p[4][5], whh1p[4][5];
#pragma unroll
    for (int k = 0; k < 4; ++k) {
        const int r = k * 10 + uc;
        const float sck = (k == 2) ? S_TANH : S_SIG;
        wih0r[k] = dWih0[r] * sck;
        b0r[k] = (dbih0[r] + dbhh0[r]) * sck;
        b1r[k] = (dbih1[r] + dbhh1[r]) * sck;
#pragma unroll
        for (int j = 0; j < 5; ++j) {
            whh0p[k][j] = mkv2(dWhh0[r * 10 + 2 * j], dWhh0[r * 10 + 2 * j + 1]) * sck;
            wih1p[k][j] = mkv2(dWih1[r * 10 + 2 * j], dWih1[r * 10 + 2 * j + 1]) * sck;
            whh1p[k][j] = mkv2(dWhh1[r * 10 + 2 * j], dWhh1[r * 10 + 2 * j + 1]) * sck;
        }
    }
    v2f outwp[5];
#pragma unroll
    for (int j = 0; j < 5; ++j) outwp[j] = mkv2(outW[2 * j], outW[2 * j + 1]);
    const float outb0 = outb[0];

    // Initial decoder state: encoder finals padded 4 -> 10 with zeros
    v2f dh0p[5], dh1p[5];
    dh0p[0] = h0p[0]; dh0p[1] = h0p[1];
    dh1p[0] = h1p[0]; dh1p[1] = h1p[1];
#pragma unroll
    for (int j = 2; j < 5; ++j) { dh0p[j] = mkv2(0.f, 0.f); dh1p[j] = mkv2(0.f, 0.f); }
    float dc0 = (lane < 4) ? c0 : 0.f;
    float dc1 = (lane < 4) ? c1 : 0.f;

    float my_noise = 0.f;

    for (int t = 0; t < T_N; ++t) {
        const float inp = dh1p[0].x;

        // L1 partial from previous h1 (independent of L0 chain)
        v2f p1[4];
#pragma unroll
        for (int k = 0; k < 4; ++k) {
            p1[k] = pk_fma(whh1p[k][0], dh1p[0], mkv2(b1r[k], 0.f));
#pragma unroll
            for (int j = 1; j < 5; ++j) p1[k] = pk_fma(whh1p[k][j], dh1p[j], p1[k]);
        }

        // L0 gates
        v2f g2[4];
#pragma unroll
        for (int k = 0; k < 4; ++k) {
            g2[k] = pk_fma(whh0p[k][0], dh0p[0], mkv2(fmaf(wih0r[k], inp, b0r[k]), 0.f));
#pragma unroll
            for (int j = 1; j < 5; ++j) g2[k] = pk_fma(whh0p[k][j], dh0p[j], g2[k]);
        }
        float iv = sig_acc(g2[0].x + g2[0].y);
        float fv = sig_acc(g2[1].x + g2[1].y);
        float gv = tanh_acc(g2[2].x + g2[2].y);
        float ov = sig_acc(g2[3].x + g2[3].y);
        dc0 = fmaf(fv, dc0, iv * gv);
        const float h0u = ov * tanh_nat(dc0);
        dh0p[0].x = dppf<0x150>(h0u); dh0p[0].y = dppf<0x151>(h0u);
        dh0p[1].x = dppf<0x152>(h0u); dh0p[1].y = dppf<0x153>(h0u);
        dh0p[2].x = dppf<0x154>(h0u); dh0p[2].y = dppf<0x155>(h0u);
        dh0p[3].x = dppf<0x156>(h0u); dh0p[3].y = dppf<0x157>(h0u);
        dh0p[4].x = dppf<0x158>(h0u); dh0p[4].y = dppf<0x159>(h0u);

        // L1 gates: accumulate the post-broadcast half into p1
#pragma unroll
        for (int k = 0; k < 4; ++k) {
#pragma unroll
            for (int j = 0; j < 5; ++j) p1[k] = pk_fma(wih1p[k][j], dh0p[j], p1[k]);
        }
        iv = sig_acc(p1[0].x + p1[0].y);
        fv = sig_acc(p1[1].x + p1[1].y);
        gv = tanh_acc(p1[2].x + p1[2].y);
        ov = sig_acc(p1[3].x + p1[3].y);
        dc1 = fmaf(fv, dc1, iv * gv);
        const float h1u = ov * tanh_nat(dc1);
        dh1p[0].x = dppf<0x150>(h1u); dh1p[0].y = dppf<0x151>(h1u);
        dh1p[1].x = dppf<0x152>(h1u); dh1p[1].y = dppf<0x153>(h1u);
        dh1p[2].x = dppf<0x154>(h1u); dh1p[2].y = dppf<0x155>(h1u);
        dh1p[3].x = dppf<0x156>(h1u); dh1p[3].y = dppf<0x157>(h1u);
        dh1p[4].x = dppf<0x158>(h1u); dh1p[4].y = dppf<0x159>(h1u);

        // noise_t = dec_out . out_W + out_b (uniform on all 16 lanes)
        v2f na = pk_fma(outwp[0], dh1p[0], mkv2(outb0, 0.f));
#pragma unroll
        for (int j = 1; j < 5; ++j) na = pk_fma(outwp[j], dh1p[j], na);
        const float nz = na.x + na.y;

        // lane u keeps t with t%16==u; flush coalesced every 16 steps
        my_noise = ((t & 15) == lane) ? nz : my_noise;
        if ((t & 15) == 15) {
            const int idx = b * T_N + (t - 15) + lane;
            out[NOISE_OFF + idx] = my_noise;
            float2 fin;
            fin.x = my_noise + fw0;
            fin.y = my_noise + fw1;
            ((float2*)out)[idx] = fin;
        }
    }
}

extern "C" void kernel_launch(void* const* d_in, const int* in_sizes, int n_in,
                              void* d_out, int out_size, void* d_ws, size_t ws_size,
                              hipStream_t stream) {
    const float* x     = (const float*)d_in[0];
    // d_in[1] = context (unused by the reference)
    const float* eWih0 = (const float*)d_in[2];
    const float* eWhh0 = (const float*)d_in[3];
    const float* ebih0 = (const float*)d_in[4];
    const float* ebhh0 = (const float*)d_in[5];
    const float* eWih1 = (const float*)d_in[6];
    const float* eWhh1 = (const float*)d_in[7];
    const float* ebih1 = (const float*)d_in[8];
    const float* ebhh1 = (const float*)d_in[9];
    const float* dWih0 = (const float*)d_in[10];
    const float* dWhh0 = (const float*)d_in[11];
    const float* dbih0 = (const float*)d_in[12];
    const float* dbhh0 = (const float*)d_in[13];
    const float* dWih1 = (const float*)d_in[14];
    const float* dWhh1 = (const float*)d_in[15];
    const float* dbih1 = (const float*)d_in[16];
    const float* dbhh1 = (const float*)d_in[17];
    const float* fcW   = (const float*)d_in[18];
    const float* fcb   = (const float*)d_in[19];
    const float* outW  = (const float*)d_in[20];
    const float* outb  = (const float*)d_in[21];

    float* out = (float*)d_out;

    // 4096 elems x 16 lanes = 65536 threads = 1024 waves = 1 wave/SIMD
    fused_kernel<<<dim3((B_N * 16) / 256), dim3(256), 0, stream>>>(
        x, eWih0, eWhh0, ebih0, ebhh0, eWih1, eWhh1, ebih1, ebhh1,
        dWih0, dWhh0, dbih0, dbhh0, dWih1, dWhh1, dbih1, dbhh1,
        fcW, fcb, outW, outb, out);
}